// Round 4
// baseline (387.562 us; speedup 1.0000x reference)
//
#include <hip/hip_runtime.h>

#define NITER 3
#define LAMBDA 0.01f
#define EPS 1e-9f
#define LOG2PI 1.8378770664093453f

#define DIN 12
#define CIN 8
#define NI 216      // 27 * 8 input capsule-taps
#define NO 16       // output capsules
#define PPAD 20     // sPT row stride (floats)
#define RSTR 216    // sRaT row stride (floats)

// 512 threads = 16 o x 32 j. Thread (o,j) owns taps i = j+32k (k=0..6, i<216),
// holds W[i][o] (4x4 each) in registers for the whole kernel, computes full
// 4x4 votes for m-step moments AND e-step logits. 1 block/CU (VGPR ~190).
__global__ __launch_bounds__(512)
void caps_em_kernel(const float* __restrict__ pose,
                    const float* __restrict__ act,
                    const float* __restrict__ W,
                    const float* __restrict__ beta_v,
                    const float* __restrict__ beta_a,
                    float* __restrict__ out)
{
    // sPT[i][c*4+k] = P[i][k*4+c]  (pose columns contiguous -> 1 b128 per vote column)
    __shared__ __align__(16) float sPT[NI][PPAD];
    __shared__ __align__(16) float sRaT[NO][RSTR];   // Ra transposed [o][i]
    __shared__ float sAct[NI];
    __shared__ __align__(16) float sPoseM[NO][16];   // row-major [o][r*4+c]
    __shared__ __align__(16) float sIvM[NO][16];
    __shared__ float sCo[NO];

    const int t = threadIdx.x;
    const int b = blockIdx.x;            // 0..999 -> (od,oh,ow)
    const int od = b / 100;
    const int rem = b - od * 100;
    const int oh = rem / 10;
    const int ow = rem - oh * 10;

    const int o = t >> 5;                // output capsule 0..15
    const int j = t & 31;                // i-lane 0..31

    // ---------- stage P (transposed) + act ----------
    for (int u = t; u < NI * 4; u += 512) {
        int i = u >> 2, q = u & 3;       // q = source row of the 4x4
        int ci = i & 7, n = i >> 3;
        int kw = n % 3, n2 = n / 3;
        int kh = n2 % 3, kd = n2 / 3;
        const float4 v = *(const float4*)&pose[((((od + kd) * DIN + (oh + kh)) * DIN + (ow + kw)) * CIN + ci) * 16 + q * 4];
        sPT[i][0 + q]  = v.x;
        sPT[i][4 + q]  = v.y;
        sPT[i][8 + q]  = v.z;
        sPT[i][12 + q] = v.w;
    }
    if (t < NI) {
        int i = t;
        int ci = i & 7, n = i >> 3;
        int kw = n % 3, n2 = n / 3;
        int kh = n2 % 3, kd = n2 / 3;
        sAct[i] = act[(((od + kd) * DIN + (oh + kh)) * DIN + (ow + kw)) * CIN + ci] + EPS;
    }

    // ---------- W register cache: W[i][o][r][:] for this thread's taps ----------
    const float4* W4 = (const float4*)W;        // idx = (i*16 + o)*4 + r
    float4 wreg[7][4];
#pragma unroll
    for (int k = 0; k < 7; ++k) {
        const int i = j + 32 * k;
        if (i < NI) {
            const float4* Wp = W4 + (i * 16 + o) * 4;
            wreg[k][0] = Wp[0];
            wreg[k][1] = Wp[1];
            wreg[k][2] = Wp[2];
            wreg[k][3] = Wp[3];
        }
    }
    const float bv_o = beta_v[o];
    const float ba_o = beta_a[o];
    __syncthreads();

    const int b4 = (j >> 4) & 1, b3 = (j >> 3) & 1, b2 = (j >> 2) & 1, b1 = (j >> 1) & 1;

    for (int it = 0; it < NITER; ++it) {
        // ---------- m-step: full 4x4 votes for own (i,o); accumulate 16 moments ----------
        float m1[16], m2[16];
#pragma unroll
        for (int q = 0; q < 16; ++q) { m1[q] = 0.f; m2[q] = 0.f; }
        float rs = 0.f;
#pragma unroll
        for (int k = 0; k < 7; ++k) {
            const int i = j + 32 * k;
            if (i < NI) {
                const float ra = (it == 0) ? sAct[i] * 0.0625f : sRaT[o][i];
                rs += ra;
#pragma unroll
                for (int cc = 0; cc < 4; ++cc) {
                    const float4 pt = *(const float4*)&sPT[i][cc * 4];
#pragma unroll
                    for (int rr = 0; rr < 4; ++rr) {
                        float v = wreg[k][rr].x * pt.x;
                        v = fmaf(wreg[k][rr].y, pt.y, v);
                        v = fmaf(wreg[k][rr].z, pt.z, v);
                        v = fmaf(wreg[k][rr].w, pt.w, v);
                        m1[rr * 4 + cc] = fmaf(ra, v, m1[rr * 4 + cc]);
                        m2[rr * 4 + cc] = fmaf(ra * v, v, m2[rr * 4 + cc]);
                    }
                }
            }
        }

        // ---------- register-halving shuffle tree over the 32 j-lanes ----------
        // After 4 halvings + final xor1, lane holds element e = j>>1 (dup over bit0).
#pragma unroll
        for (int q = 0; q < 8; ++q) {
            float s1 = b4 ? m1[q] : m1[q + 8];
            float s2 = b4 ? m2[q] : m2[q + 8];
            m1[q] = (b4 ? m1[q + 8] : m1[q]) + __shfl_xor(s1, 16);
            m2[q] = (b4 ? m2[q + 8] : m2[q]) + __shfl_xor(s2, 16);
        }
#pragma unroll
        for (int q = 0; q < 4; ++q) {
            float s1 = b3 ? m1[q] : m1[q + 4];
            float s2 = b3 ? m2[q] : m2[q + 4];
            m1[q] = (b3 ? m1[q + 4] : m1[q]) + __shfl_xor(s1, 8);
            m2[q] = (b3 ? m2[q + 4] : m2[q]) + __shfl_xor(s2, 8);
        }
#pragma unroll
        for (int q = 0; q < 2; ++q) {
            float s1 = b2 ? m1[q] : m1[q + 2];
            float s2 = b2 ? m2[q] : m2[q + 2];
            m1[q] = (b2 ? m1[q + 2] : m1[q]) + __shfl_xor(s1, 4);
            m2[q] = (b2 ? m2[q + 2] : m2[q]) + __shfl_xor(s2, 4);
        }
        {
            float s1 = b1 ? m1[0] : m1[1];
            float s2 = b1 ? m2[0] : m2[1];
            m1[0] = (b1 ? m1[1] : m1[0]) + __shfl_xor(s1, 2);
            m2[0] = (b1 ? m2[1] : m2[0]) + __shfl_xor(s2, 2);
        }
        m1[0] += __shfl_xor(m1[0], 1);
        m2[0] += __shfl_xor(m2[0], 1);
        rs += __shfl_xor(rs, 16);
        rs += __shfl_xor(rs, 8);
        rs += __shfl_xor(rs, 4);
        rs += __shfl_xor(rs, 2);
        rs += __shfl_xor(rs, 1);
        const int e = j >> 1;            // this lane's pose element (row-major)

        const float inv_rs = 1.0f / rs;
        const float pe = m1[0] * inv_rs;
        const float ve = fmaxf(m2[0] * inv_rs - pe * pe, 0.0f) + EPS;
        const float lv = __logf(ve);

        // SL = sum log_var over the 16 elements (each e lives on 2 lanes -> x0.5)
        float SL = lv;
        SL += __shfl_xor(SL, 1);
        SL += __shfl_xor(SL, 2);
        SL += __shfl_xor(SL, 4);
        SL += __shfl_xor(SL, 8);
        SL += __shfl_xor(SL, 16);
        SL *= 0.5f;

        const float cost  = rs * (16.0f * bv_o + 0.5f * SL);
        const float logit = LAMBDA * (ba_o - cost);

        if (it == NITER - 1) {
            if ((j & 1) == 0) out[(b * NO + o) * 16 + e] = pe;
            if (j == 0) out[256000 + b * NO + o] = 1.0f / (1.0f + __expf(-logit));
            return;
        }

        const float log_a = (logit >= 0.0f) ? -log1pf(__expf(-logit))
                                            : logit - log1pf(__expf(logit));
        if ((j & 1) == 0) {
            sPoseM[o][e] = pe;
            sIvM[o][e]   = 1.0f / ve;
        }
        if (j == 0) sCo[o] = log_a - 0.5f * SL - 8.0f * LOG2PI;
        __syncthreads();   // B2: pose/iv/Co ready

        // ---------- e-step: recompute votes from wreg, q-form, write logits ----------
        {
            float pv[16], iv16[16];
            *(float4*)&pv[0]    = *(const float4*)&sPoseM[o][0];
            *(float4*)&pv[4]    = *(const float4*)&sPoseM[o][4];
            *(float4*)&pv[8]    = *(const float4*)&sPoseM[o][8];
            *(float4*)&pv[12]   = *(const float4*)&sPoseM[o][12];
            *(float4*)&iv16[0]  = *(const float4*)&sIvM[o][0];
            *(float4*)&iv16[4]  = *(const float4*)&sIvM[o][4];
            *(float4*)&iv16[8]  = *(const float4*)&sIvM[o][8];
            *(float4*)&iv16[12] = *(const float4*)&sIvM[o][12];
            const float Co = sCo[o];
#pragma unroll
            for (int k = 0; k < 7; ++k) {
                const int i = j + 32 * k;
                if (i < NI) {
                    float q = 0.f;
#pragma unroll
                    for (int cc = 0; cc < 4; ++cc) {
                        const float4 pt = *(const float4*)&sPT[i][cc * 4];
#pragma unroll
                        for (int rr = 0; rr < 4; ++rr) {
                            float v = wreg[k][rr].x * pt.x;
                            v = fmaf(wreg[k][rr].y, pt.y, v);
                            v = fmaf(wreg[k][rr].z, pt.z, v);
                            v = fmaf(wreg[k][rr].w, pt.w, v);
                            const float d = v - pv[rr * 4 + cc];
                            q = fmaf(d * d, iv16[rr * 4 + cc], q);
                        }
                    }
                    sRaT[o][i] = Co - 0.5f * q;   // pre-normalization logit
                }
            }
        }
        __syncthreads();   // B3: logits ready

        // ---------- R update: softmax over o, times act ----------
        if (t < NI) {
            float l[16];
            float mx = -1e30f;
#pragma unroll
            for (int oo = 0; oo < 16; ++oo) { l[oo] = sRaT[oo][t]; mx = fmaxf(mx, l[oo]); }
            float s = 0.f;
#pragma unroll
            for (int oo = 0; oo < 16; ++oo) { l[oo] = __expf(l[oo] - mx); s += l[oo]; }
            const float sc = sAct[t] / s;
#pragma unroll
            for (int oo = 0; oo < 16; ++oo) sRaT[oo][t] = sc * l[oo];
        }
        __syncthreads();   // B4: Ra ready
    }
}

extern "C" void kernel_launch(void* const* d_in, const int* in_sizes, int n_in,
                              void* d_out, int out_size, void* d_ws, size_t ws_size,
                              hipStream_t stream) {
    const float* pose = (const float*)d_in[0];
    const float* actv = (const float*)d_in[1];
    const float* W    = (const float*)d_in[2];
    const float* bv   = (const float*)d_in[3];
    const float* ba   = (const float*)d_in[4];
    float* out = (float*)d_out;
    caps_em_kernel<<<dim3(1000), dim3(512), 0, stream>>>(pose, actv, W, bv, ba, out);
}

// Round 5
// 146.844 us; speedup vs baseline: 2.6393x; 2.6393x over previous
//
#include <hip/hip_runtime.h>

#define NITER 3
#define LAMBDA 0.01f
#define EPS 1e-9f
#define LOG2PI 1.8378770664093453f

#define DIN 12
#define CIN 8
#define NI 216      // 27 * 8 input capsule-taps
#define NO 16       // output capsules
#define PPAD 20     // sPT row stride (floats)
#define RSTR 216    // sRaT row stride (floats)

// 512 threads = 16 o x 32 j. Thread (o,j) owns taps i = j+32k (k=0..6, padded to 224),
// holds W[i][o] (4x4 each) in registers for the whole kernel, computes full 4x4 votes
// for m-step moments AND e-step logits. launch_bounds(512,2): VGPR cap 256 -> no spill.
__global__ __launch_bounds__(512, 2)
void caps_em_kernel(const float* __restrict__ pose,
                    const float* __restrict__ act,
                    const float* __restrict__ W,
                    const float* __restrict__ beta_v,
                    const float* __restrict__ beta_a,
                    float* __restrict__ out)
{
    // sPT[i][c*4+k] = P[i][k*4+c]  (pose columns contiguous -> 1 b128 per vote column)
    __shared__ __align__(16) float sPT[NI][PPAD];
    __shared__ __align__(16) float sRaT[NO][RSTR];   // Ra transposed [o][i]
    __shared__ float sAct[NI];
    __shared__ __align__(16) float sPoseM[NO][16];   // row-major [o][r*4+c]
    __shared__ __align__(16) float sIvM[NO][16];
    __shared__ float sCo[NO];

    const int t = threadIdx.x;
    const int b = blockIdx.x;            // 0..999 -> (od,oh,ow)
    const int od = b / 100;
    const int rem = b - od * 100;
    const int oh = rem / 10;
    const int ow = rem - oh * 10;

    const int o = t >> 5;                // output capsule 0..15
    const int j = t & 31;                // i-lane 0..31

    // ---------- stage P (transposed) + act ----------
    for (int u = t; u < NI * 4; u += 512) {
        int i = u >> 2, q = u & 3;       // q = source row of the 4x4
        int ci = i & 7, n = i >> 3;
        int kw = n % 3, n2 = n / 3;
        int kh = n2 % 3, kd = n2 / 3;
        const float4 v = *(const float4*)&pose[((((od + kd) * DIN + (oh + kh)) * DIN + (ow + kw)) * CIN + ci) * 16 + q * 4];
        sPT[i][0 + q]  = v.x;
        sPT[i][4 + q]  = v.y;
        sPT[i][8 + q]  = v.z;
        sPT[i][12 + q] = v.w;
    }
    if (t < NI) {
        int i = t;
        int ci = i & 7, n = i >> 3;
        int kw = n % 3, n2 = n / 3;
        int kh = n2 % 3, kd = n2 / 3;
        sAct[i] = act[(((od + kd) * DIN + (oh + kh)) * DIN + (ow + kw)) * CIN + ci] + EPS;
    }

    // ---------- W register cache: W[i][o][r][:] for this thread's taps (padded) ----------
    const float4* W4 = (const float4*)W;        // idx = (i*16 + o)*4 + r
    float4 wreg[7][4];
#pragma unroll
    for (int k = 0; k < 7; ++k) {
        const int iw = min(j + 32 * k, NI - 1);   // clamp pad taps (ra=0 kills their votes)
        const float4* Wp = W4 + (iw * 16 + o) * 4;
        wreg[k][0] = Wp[0];
        wreg[k][1] = Wp[1];
        wreg[k][2] = Wp[2];
        wreg[k][3] = Wp[3];
    }
    const float bv_o = beta_v[o];
    const float ba_o = beta_a[o];
    __syncthreads();

    const int b4 = (j >> 4) & 1, b3 = (j >> 3) & 1, b2 = (j >> 2) & 1, b1 = (j >> 1) & 1;
    const bool lastPartial = (j >= 24);  // k=6 tap i=192+j valid only for j<24

    for (int it = 0; it < NITER; ++it) {
        // ---------- m-step: full 4x4 votes for own (i,o); accumulate 16 moments ----------
        float m1[16], m2[16];
#pragma unroll
        for (int q = 0; q < 16; ++q) { m1[q] = 0.f; m2[q] = 0.f; }
        float rs = 0.f;
#pragma unroll
        for (int k = 0; k < 7; ++k) {
            const int i = j + 32 * k;
            const int ip = min(i, NI - 1);
            float ra = (it == 0) ? sAct[ip] * 0.0625f : sRaT[o][ip];
            if (k == 6 && lastPartial) ra = 0.f;   // pad taps contribute nothing
            rs += ra;
#pragma unroll
            for (int cc = 0; cc < 4; ++cc) {
                const float4 pt = *(const float4*)&sPT[ip][cc * 4];
#pragma unroll
                for (int rr = 0; rr < 4; ++rr) {
                    float v = wreg[k][rr].x * pt.x;
                    v = fmaf(wreg[k][rr].y, pt.y, v);
                    v = fmaf(wreg[k][rr].z, pt.z, v);
                    v = fmaf(wreg[k][rr].w, pt.w, v);
                    m1[rr * 4 + cc] = fmaf(ra, v, m1[rr * 4 + cc]);
                    m2[rr * 4 + cc] = fmaf(ra * v, v, m2[rr * 4 + cc]);
                }
            }
        }

        // ---------- register-halving shuffle tree over the 32 j-lanes ----------
        // After 4 halvings + final xor1, lane holds element e = j>>1 (dup over bit0).
#pragma unroll
        for (int q = 0; q < 8; ++q) {
            float s1 = b4 ? m1[q] : m1[q + 8];
            float s2 = b4 ? m2[q] : m2[q + 8];
            m1[q] = (b4 ? m1[q + 8] : m1[q]) + __shfl_xor(s1, 16);
            m2[q] = (b4 ? m2[q + 8] : m2[q]) + __shfl_xor(s2, 16);
        }
#pragma unroll
        for (int q = 0; q < 4; ++q) {
            float s1 = b3 ? m1[q] : m1[q + 4];
            float s2 = b3 ? m2[q] : m2[q + 4];
            m1[q] = (b3 ? m1[q + 4] : m1[q]) + __shfl_xor(s1, 8);
            m2[q] = (b3 ? m2[q + 4] : m2[q]) + __shfl_xor(s2, 8);
        }
#pragma unroll
        for (int q = 0; q < 2; ++q) {
            float s1 = b2 ? m1[q] : m1[q + 2];
            float s2 = b2 ? m2[q] : m2[q + 2];
            m1[q] = (b2 ? m1[q + 2] : m1[q]) + __shfl_xor(s1, 4);
            m2[q] = (b2 ? m2[q + 2] : m2[q]) + __shfl_xor(s2, 4);
        }
        {
            float s1 = b1 ? m1[0] : m1[1];
            float s2 = b1 ? m2[0] : m2[1];
            m1[0] = (b1 ? m1[1] : m1[0]) + __shfl_xor(s1, 2);
            m2[0] = (b1 ? m2[1] : m2[0]) + __shfl_xor(s2, 2);
        }
        m1[0] += __shfl_xor(m1[0], 1);
        m2[0] += __shfl_xor(m2[0], 1);
        rs += __shfl_xor(rs, 16);
        rs += __shfl_xor(rs, 8);
        rs += __shfl_xor(rs, 4);
        rs += __shfl_xor(rs, 2);
        rs += __shfl_xor(rs, 1);
        const int e = j >> 1;            // this lane's pose element (row-major)

        const float inv_rs = 1.0f / rs;
        const float pe = m1[0] * inv_rs;
        const float ve = fmaxf(m2[0] * inv_rs - pe * pe, 0.0f) + EPS;
        const float lv = __logf(ve);

        // SL = sum log_var over the 16 elements (each e lives on 2 lanes -> x0.5)
        float SL = lv;
        SL += __shfl_xor(SL, 1);
        SL += __shfl_xor(SL, 2);
        SL += __shfl_xor(SL, 4);
        SL += __shfl_xor(SL, 8);
        SL += __shfl_xor(SL, 16);
        SL *= 0.5f;

        const float cost  = rs * (16.0f * bv_o + 0.5f * SL);
        const float logit = LAMBDA * (ba_o - cost);

        if (it == NITER - 1) {
            if ((j & 1) == 0) out[(b * NO + o) * 16 + e] = pe;
            if (j == 0) out[256000 + b * NO + o] = 1.0f / (1.0f + __expf(-logit));
            return;
        }

        const float log_a = (logit >= 0.0f) ? -log1pf(__expf(-logit))
                                            : logit - log1pf(__expf(logit));
        if ((j & 1) == 0) {
            sPoseM[o][e] = pe;
            sIvM[o][e]   = 1.0f / ve;
        }
        if (j == 0) sCo[o] = log_a - 0.5f * SL - 8.0f * LOG2PI;
        __syncthreads();   // B2: pose/iv/Co ready

        // ---------- e-step: recompute votes from wreg, q-form, write logits ----------
        {
            float pv[16], iv16[16];
            *(float4*)&pv[0]    = *(const float4*)&sPoseM[o][0];
            *(float4*)&pv[4]    = *(const float4*)&sPoseM[o][4];
            *(float4*)&pv[8]    = *(const float4*)&sPoseM[o][8];
            *(float4*)&pv[12]   = *(const float4*)&sPoseM[o][12];
            *(float4*)&iv16[0]  = *(const float4*)&sIvM[o][0];
            *(float4*)&iv16[4]  = *(const float4*)&sIvM[o][4];
            *(float4*)&iv16[8]  = *(const float4*)&sIvM[o][8];
            *(float4*)&iv16[12] = *(const float4*)&sIvM[o][12];
            const float Co = sCo[o];
#pragma unroll
            for (int k = 0; k < 7; ++k) {
                const int i = j + 32 * k;
                const int ip = min(i, NI - 1);
                float q = 0.f;
#pragma unroll
                for (int cc = 0; cc < 4; ++cc) {
                    const float4 pt = *(const float4*)&sPT[ip][cc * 4];
#pragma unroll
                    for (int rr = 0; rr < 4; ++rr) {
                        float v = wreg[k][rr].x * pt.x;
                        v = fmaf(wreg[k][rr].y, pt.y, v);
                        v = fmaf(wreg[k][rr].z, pt.z, v);
                        v = fmaf(wreg[k][rr].w, pt.w, v);
                        const float d = v - pv[rr * 4 + cc];
                        q = fmaf(d * d, iv16[rr * 4 + cc], q);
                    }
                }
                if (!(k == 6 && lastPartial)) {
                    sRaT[o][i] = Co - 0.5f * q;   // pre-normalization logit
                }
            }
        }
        __syncthreads();   // B3: logits ready

        // ---------- R update: softmax over o, times act ----------
        if (t < NI) {
            float l[16];
            float mx = -1e30f;
#pragma unroll
            for (int oo = 0; oo < 16; ++oo) { l[oo] = sRaT[oo][t]; mx = fmaxf(mx, l[oo]); }
            float s = 0.f;
#pragma unroll
            for (int oo = 0; oo < 16; ++oo) { l[oo] = __expf(l[oo] - mx); s += l[oo]; }
            const float sc = sAct[t] / s;
#pragma unroll
            for (int oo = 0; oo < 16; ++oo) sRaT[oo][t] = sc * l[oo];
        }
        __syncthreads();   // B4: Ra ready
    }
}

extern "C" void kernel_launch(void* const* d_in, const int* in_sizes, int n_in,
                              void* d_out, int out_size, void* d_ws, size_t ws_size,
                              hipStream_t stream) {
    const float* pose = (const float*)d_in[0];
    const float* actv = (const float*)d_in[1];
    const float* W    = (const float*)d_in[2];
    const float* bv   = (const float*)d_in[3];
    const float* ba   = (const float*)d_in[4];
    float* out = (float*)d_out;
    caps_em_kernel<<<dim3(1000), dim3(512), 0, stream>>>(pose, actv, W, bv, ba, out);
}

// Round 8
// 131.932 us; speedup vs baseline: 2.9376x; 1.1130x over previous
//
#include <hip/hip_runtime.h>

#define NITER 3
#define LAMBDA 0.01f
#define EPS 1e-9f
#define LOG2PI 1.8378770664093453f

#define DIN 12
#define CIN 8
#define NI 216      // 27 * 8 input capsule-taps
#define NO 16       // output capsules
#define PPAD 20     // sPT row stride (floats)
#define RSTR 216    // sRaT row stride (floats)

// 512 threads = 16 o x 32 j. Thread (o,j) owns taps i = j+32k (k=0..6, padded to 224).
// Votes v[i][o][0..15] are iteration-invariant -> computed ONCE into registers
// (vo[7][16], 112 VGPR); all 3 m-passes and 2 e-passes consume stored votes.
// amdgpu_waves_per_eu(2,2): VGPR cap 256, RA must not squeeze to 128 (R4 lesson).
__global__ __launch_bounds__(512) __attribute__((amdgpu_waves_per_eu(2, 2)))
void caps_em_kernel(const float* __restrict__ pose,
                    const float* __restrict__ act,
                    const float* __restrict__ W,
                    const float* __restrict__ beta_v,
                    const float* __restrict__ beta_a,
                    float* __restrict__ out)
{
    // sPT[i][c*4+k] = P[i][k*4+c]  (pose columns contiguous; prologue-only use)
    __shared__ __align__(16) float sPT[NI][PPAD];
    __shared__ __align__(16) float sRaT[NO][RSTR];   // Ra transposed [o][i]
    __shared__ float sAct[NI];
    __shared__ __align__(16) float sPoseM[NO][16];   // row-major [o][r*4+c]
    __shared__ __align__(16) float sIvM[NO][16];
    __shared__ float sCo[NO];

    const int t = threadIdx.x;
    const int b = blockIdx.x;            // 0..999 -> (od,oh,ow)
    const int od = b / 100;
    const int rem = b - od * 100;
    const int oh = rem / 10;
    const int ow = rem - oh * 10;

    const int o = t >> 5;                // output capsule 0..15
    const int j = t & 31;                // i-lane 0..31

    // ---------- W loads issued first (latency hides under LDS staging) ----------
    const float4* W4 = (const float4*)W;        // idx = (i*16 + o)*4 + r
    float4 w[7][4];
#pragma unroll
    for (int k = 0; k < 7; ++k) {
        const int iw = min(j + 32 * k, NI - 1);   // clamp pad taps (ra=0 kills them)
        const float4* Wp = W4 + (iw * 16 + o) * 4;
        w[k][0] = Wp[0];
        w[k][1] = Wp[1];
        w[k][2] = Wp[2];
        w[k][3] = Wp[3];
    }

    // ---------- stage P (transposed) + act ----------
    for (int u = t; u < NI * 4; u += 512) {
        int i = u >> 2, q = u & 3;       // q = source row of the 4x4
        int ci = i & 7, n = i >> 3;
        int kw = n % 3, n2 = n / 3;
        int kh = n2 % 3, kd = n2 / 3;
        const float4 v = *(const float4*)&pose[((((od + kd) * DIN + (oh + kh)) * DIN + (ow + kw)) * CIN + ci) * 16 + q * 4];
        sPT[i][0 + q]  = v.x;
        sPT[i][4 + q]  = v.y;
        sPT[i][8 + q]  = v.z;
        sPT[i][12 + q] = v.w;
    }
    if (t < NI) {
        int i = t;
        int ci = i & 7, n = i >> 3;
        int kw = n % 3, n2 = n / 3;
        int kh = n2 % 3, kd = n2 / 3;
        sAct[i] = act[(((od + kd) * DIN + (oh + kh)) * DIN + (ow + kw)) * CIN + ci] + EPS;
    }
    const float bv_o = beta_v[o];
    const float ba_o = beta_a[o];
    __syncthreads();

    // ---------- compute votes ONCE into registers: vo[k][rr*4+cc] ----------
    float vo[7][16];
#pragma unroll
    for (int k = 0; k < 7; ++k) {
        const int ip = min(j + 32 * k, NI - 1);
#pragma unroll
        for (int cc = 0; cc < 4; ++cc) {
            const float4 pt = *(const float4*)&sPT[ip][cc * 4];   // P[0..3][cc]
#pragma unroll
            for (int rr = 0; rr < 4; ++rr) {
                float v = w[k][rr].x * pt.x;
                v = fmaf(w[k][rr].y, pt.y, v);
                v = fmaf(w[k][rr].z, pt.z, v);
                v = fmaf(w[k][rr].w, pt.w, v);
                vo[k][rr * 4 + cc] = v;
            }
        }
    }

    const int b4 = (j >> 4) & 1, b3 = (j >> 3) & 1, b2 = (j >> 2) & 1, b1 = (j >> 1) & 1;
    const bool lastPartial = (j >= 24);  // k=6 tap i=192+j valid only for j<24

    for (int it = 0; it < NITER; ++it) {
        // ---------- m-step: moments from stored votes ----------
        float m1[16], m2[16];
#pragma unroll
        for (int q = 0; q < 16; ++q) { m1[q] = 0.f; m2[q] = 0.f; }
        float rs = 0.f;
#pragma unroll
        for (int k = 0; k < 7; ++k) {
            const int ip = min(j + 32 * k, NI - 1);
            float ra = (it == 0) ? sAct[ip] * 0.0625f : sRaT[o][ip];
            if (k == 6 && lastPartial) ra = 0.f;   // pad taps contribute nothing
            rs += ra;
#pragma unroll
            for (int q = 0; q < 16; ++q) {
                const float v  = vo[k][q];
                const float rv = ra * v;
                m1[q] += rv;
                m2[q] = fmaf(rv, v, m2[q]);
            }
        }

        // ---------- register-halving shuffle tree over the 32 j-lanes ----------
        // After 4 halvings + final xor1, lane holds element e = j>>1 (dup over bit0).
#pragma unroll
        for (int q = 0; q < 8; ++q) {
            float s1 = b4 ? m1[q] : m1[q + 8];
            float s2 = b4 ? m2[q] : m2[q + 8];
            m1[q] = (b4 ? m1[q + 8] : m1[q]) + __shfl_xor(s1, 16);
            m2[q] = (b4 ? m2[q + 8] : m2[q]) + __shfl_xor(s2, 16);
        }
#pragma unroll
        for (int q = 0; q < 4; ++q) {
            float s1 = b3 ? m1[q] : m1[q + 4];
            float s2 = b3 ? m2[q] : m2[q + 4];
            m1[q] = (b3 ? m1[q + 4] : m1[q]) + __shfl_xor(s1, 8);
            m2[q] = (b3 ? m2[q + 4] : m2[q]) + __shfl_xor(s2, 8);
        }
#pragma unroll
        for (int q = 0; q < 2; ++q) {
            float s1 = b2 ? m1[q] : m1[q + 2];
            float s2 = b2 ? m2[q] : m2[q + 2];
            m1[q] = (b2 ? m1[q + 2] : m1[q]) + __shfl_xor(s1, 4);
            m2[q] = (b2 ? m2[q + 2] : m2[q]) + __shfl_xor(s2, 4);
        }
        {
            float s1 = b1 ? m1[0] : m1[1];
            float s2 = b1 ? m2[0] : m2[1];
            m1[0] = (b1 ? m1[1] : m1[0]) + __shfl_xor(s1, 2);
            m2[0] = (b1 ? m2[1] : m2[0]) + __shfl_xor(s2, 2);
        }
        m1[0] += __shfl_xor(m1[0], 1);
        m2[0] += __shfl_xor(m2[0], 1);
        rs += __shfl_xor(rs, 16);
        rs += __shfl_xor(rs, 8);
        rs += __shfl_xor(rs, 4);
        rs += __shfl_xor(rs, 2);
        rs += __shfl_xor(rs, 1);
        const int e = j >> 1;            // this lane's pose element (row-major)

        const float inv_rs = 1.0f / rs;
        const float pe = m1[0] * inv_rs;
        const float ve = fmaxf(m2[0] * inv_rs - pe * pe, 0.0f) + EPS;
        const float lv = __logf(ve);

        // SL = sum log_var over the 16 elements (each e lives on 2 lanes -> x0.5)
        float SL = lv;
        SL += __shfl_xor(SL, 1);
        SL += __shfl_xor(SL, 2);
        SL += __shfl_xor(SL, 4);
        SL += __shfl_xor(SL, 8);
        SL += __shfl_xor(SL, 16);
        SL *= 0.5f;

        const float cost  = rs * (16.0f * bv_o + 0.5f * SL);
        const float logit = LAMBDA * (ba_o - cost);

        if (it == NITER - 1) {
            if ((j & 1) == 0) out[(b * NO + o) * 16 + e] = pe;
            if (j == 0) out[256000 + b * NO + o] = 1.0f / (1.0f + __expf(-logit));
            return;
        }

        const float log_a = (logit >= 0.0f) ? -log1pf(__expf(-logit))
                                            : logit - log1pf(__expf(logit));
        if ((j & 1) == 0) {
            sPoseM[o][e] = pe;
            sIvM[o][e]   = 1.0f / ve;
        }
        if (j == 0) sCo[o] = log_a - 0.5f * SL - 8.0f * LOG2PI;
        __syncthreads();   // B2: pose/iv/Co ready

        // ---------- e-step: q-form from stored votes ----------
        {
            float pv[16], iv16[16];
            *(float4*)&pv[0]    = *(const float4*)&sPoseM[o][0];
            *(float4*)&pv[4]    = *(const float4*)&sPoseM[o][4];
            *(float4*)&pv[8]    = *(const float4*)&sPoseM[o][8];
            *(float4*)&pv[12]   = *(const float4*)&sPoseM[o][12];
            *(float4*)&iv16[0]  = *(const float4*)&sIvM[o][0];
            *(float4*)&iv16[4]  = *(const float4*)&sIvM[o][4];
            *(float4*)&iv16[8]  = *(const float4*)&sIvM[o][8];
            *(float4*)&iv16[12] = *(const float4*)&sIvM[o][12];
            const float Co = sCo[o];
#pragma unroll
            for (int k = 0; k < 7; ++k) {
                const int i = j + 32 * k;
                float q = 0.f;
#pragma unroll
                for (int qq = 0; qq < 16; ++qq) {
                    const float d = vo[k][qq] - pv[qq];
                    q = fmaf(d * d, iv16[qq], q);
                }
                if (!(k == 6 && lastPartial)) {
                    sRaT[o][i] = Co - 0.5f * q;   // pre-normalization logit
                }
            }
        }
        __syncthreads();   // B3: logits ready

        // ---------- R update: softmax over o, times act ----------
        if (t < NI) {
            float l[16];
            float mx = -1e30f;
#pragma unroll
            for (int oo = 0; oo < 16; ++oo) { l[oo] = sRaT[oo][t]; mx = fmaxf(mx, l[oo]); }
            float s = 0.f;
#pragma unroll
            for (int oo = 0; oo < 16; ++oo) { l[oo] = __expf(l[oo] - mx); s += l[oo]; }
            const float sc = sAct[t] / s;
#pragma unroll
            for (int oo = 0; oo < 16; ++oo) sRaT[oo][t] = sc * l[oo];
        }
        __syncthreads();   // B4: Ra ready
    }
}

extern "C" void kernel_launch(void* const* d_in, const int* in_sizes, int n_in,
                              void* d_out, int out_size, void* d_ws, size_t ws_size,
                              hipStream_t stream) {
    const float* pose = (const float*)d_in[0];
    const float* actv = (const float*)d_in[1];
    const float* W    = (const float*)d_in[2];
    const float* bv   = (const float*)d_in[3];
    const float* ba   = (const float*)d_in[4];
    float* out = (float*)d_out;
    caps_em_kernel<<<dim3(1000), dim3(512), 0, stream>>>(pose, actv, W, bv, ba, out);
}